// Round 1
// baseline (183.884 us; speedup 1.0000x reference)
//
#include <hip/hip_runtime.h>
#include <math.h>

#define BLOCK 256
#define NF 32
#define NDOF 29

__global__ __launch_bounds__(BLOCK) void fk_kernel(
    const float* __restrict__ ja,       // (B,29)
    const float* __restrict__ axes,     // (32,3)
    const float* __restrict__ origins,  // (32,4,4)
    const float* __restrict__ mmul,     // (2,)
    const float* __restrict__ moff,     // (2,)
    const int*   __restrict__ ctrl,     // (29,)
    const int*   __restrict__ msrc,     // (2,)
    const int*   __restrict__ mdst,     // (2,)
    const int*   __restrict__ types,    // (32,)
    float*       __restrict__ out,      // (B,32,4,4)
    int B)
{
    __shared__ float s_ax[NF][3];
    __shared__ float s_or[NF][12];      // top 3 rows of each origin
    __shared__ int   s_type[NF];
    __shared__ int   s_slot[NF];
    __shared__ float s_mult[NF];
    __shared__ float s_off[NF];
    __shared__ float s_ja[BLOCK * NDOF];

    const int tid = threadIdx.x;

    if (tid < NF) {
        const int f = tid;
        s_ax[f][0] = axes[f*3+0];
        s_ax[f][1] = axes[f*3+1];
        s_ax[f][2] = axes[f*3+2];
        #pragma unroll
        for (int r = 0; r < 3; ++r)
            #pragma unroll
            for (int c = 0; c < 4; ++c)
                s_or[f][r*4+c] = origins[f*16 + r*4 + c];
        s_type[f] = types[f];
        // fold ctrl scatter + mimic joints into: angle = mult * ja[slot] + off
        int slot = -1;
        for (int j = 0; j < NDOF; ++j) if (ctrl[j] == f) slot = j;
        float mu = 1.0f, of = 0.0f;
        for (int m = 0; m < 2; ++m) {
            if (mdst[m] == f) {
                const int sf = msrc[m];
                for (int j = 0; j < NDOF; ++j) if (ctrl[j] == sf) slot = j;
                mu = mmul[m]; of = moff[m];
            }
        }
        s_slot[f] = slot; s_mult[f] = mu; s_off[f] = of;
    }

    // coalesced stage of this block's joint angles into LDS
    const long blk0 = (long)blockIdx.x * BLOCK;
    {
        const long base = blk0 * NDOF;
        const long lim  = (long)B * NDOF;
        for (int i = tid; i < BLOCK * NDOF; i += BLOCK) {
            const long g = base + i;
            s_ja[i] = (g < lim) ? ja[g] : 0.0f;
        }
    }
    __syncthreads();

    const long b = blk0 + tid;
    if (b >= B) return;

    float4* __restrict__ outp = (float4*)(out + b * 512);

    float Pr[9], Pt[3];   // running chain pose (3x4 affine)
    float Qr[9], Qt[3];   // saved pose of frame 10 (for leaves 30,31)

    auto compute_local = [&](int f, float* Lr, float* Lt) {
        const int   slot = s_slot[f];
        const float a = (slot >= 0) ? fmaf(s_mult[f], s_ja[tid*NDOF + slot], s_off[f]) : 0.0f;
        const float wx = a * s_ax[f][0];
        const float wy = a * s_ax[f][1];
        const float wz = a * s_ax[f][2];
        const int ty = s_type[f];
        float R0,R1,R2,R3,R4,R5,R6,R7,R8;
        if (ty == 1) {
            const float t2 = wx*wx + wy*wy + wz*wz;
            const float th = sqrtf(t2 + 1e-18f);
            const float inv = 1.0f / th;
            const float kx = wx*inv, ky = wy*inv, kz = wz*inv;
            float s, c;
            __sincosf(th, &s, &c);
            const float v = 1.0f - c;
            R0 = fmaf(v*kx, kx, c);
            R1 = v*kx*ky - s*kz;
            R2 = v*kx*kz + s*ky;
            R3 = v*kx*ky + s*kz;
            R4 = fmaf(v*ky, ky, c);
            R5 = v*ky*kz - s*kx;
            R6 = v*kx*kz - s*ky;
            R7 = v*ky*kz + s*kx;
            R8 = fmaf(v*kz, kz, c);
        } else {
            R0=1.f;R1=0.f;R2=0.f;R3=0.f;R4=1.f;R5=0.f;R6=0.f;R7=0.f;R8=1.f;
        }
        float tx, tyv, tz;
        if (ty == 2) { tx = wx; tyv = wy; tz = wz; }
        else         { tx = 0.f; tyv = 0.f; tz = 0.f; }
        const float* O = s_or[f];
        #pragma unroll
        for (int r = 0; r < 3; ++r) {
            const float o0 = O[r*4+0], o1 = O[r*4+1], o2 = O[r*4+2], o3 = O[r*4+3];
            Lr[r*3+0] = o0*R0 + o1*R3 + o2*R6;
            Lr[r*3+1] = o0*R1 + o1*R4 + o2*R7;
            Lr[r*3+2] = o0*R2 + o1*R5 + o2*R8;
            Lt[r]     = o0*tx + o1*tyv + o2*tz + o3;
        }
    };

    auto store_pose = [&](int f, const float* r, const float* t) {
        outp[f*4+0] = make_float4(r[0], r[1], r[2], t[0]);
        outp[f*4+1] = make_float4(r[3], r[4], r[5], t[1]);
        outp[f*4+2] = make_float4(r[6], r[7], r[8], t[2]);
        outp[f*4+3] = make_float4(0.0f, 0.0f, 0.0f, 1.0f);
    };

    // frame 0 (root)
    {
        float Lr[9], Lt[3];
        compute_local(0, Lr, Lt);
        #pragma unroll
        for (int i = 0; i < 9; ++i) Pr[i] = Lr[i];
        Pt[0] = Lt[0]; Pt[1] = Lt[1]; Pt[2] = Lt[2];
        store_pose(0, Pr, Pt);
    }

    // serial chain frames 1..29
    #pragma unroll 1
    for (int f = 1; f <= 29; ++f) {
        float Lr[9], Lt[3], Nr[9], Nt[3];
        compute_local(f, Lr, Lt);
        #pragma unroll
        for (int r = 0; r < 3; ++r) {
            const float p0 = Pr[r*3+0], p1 = Pr[r*3+1], p2 = Pr[r*3+2];
            Nr[r*3+0] = p0*Lr[0] + p1*Lr[3] + p2*Lr[6];
            Nr[r*3+1] = p0*Lr[1] + p1*Lr[4] + p2*Lr[7];
            Nr[r*3+2] = p0*Lr[2] + p1*Lr[5] + p2*Lr[8];
            Nt[r]     = p0*Lt[0] + p1*Lt[1] + p2*Lt[2] + Pt[r];
        }
        #pragma unroll
        for (int i = 0; i < 9; ++i) Pr[i] = Nr[i];
        Pt[0] = Nt[0]; Pt[1] = Nt[1]; Pt[2] = Nt[2];
        store_pose(f, Pr, Pt);
        if (f == 10) {
            #pragma unroll
            for (int i = 0; i < 9; ++i) Qr[i] = Pr[i];
            Qt[0] = Pt[0]; Qt[1] = Pt[1]; Qt[2] = Pt[2];
        }
    }

    // leaf frames 30,31 hang off frame 10
    #pragma unroll 1
    for (int f = 30; f < 32; ++f) {
        float Lr[9], Lt[3], Nr[9], Nt[3];
        compute_local(f, Lr, Lt);
        #pragma unroll
        for (int r = 0; r < 3; ++r) {
            const float p0 = Qr[r*3+0], p1 = Qr[r*3+1], p2 = Qr[r*3+2];
            Nr[r*3+0] = p0*Lr[0] + p1*Lr[3] + p2*Lr[6];
            Nr[r*3+1] = p0*Lr[1] + p1*Lr[4] + p2*Lr[7];
            Nr[r*3+2] = p0*Lr[2] + p1*Lr[5] + p2*Lr[8];
            Nt[r]     = p0*Lt[0] + p1*Lt[1] + p2*Lt[2] + Qt[r];
        }
        store_pose(f, Nr, Nt);
    }
}

extern "C" void kernel_launch(void* const* d_in, const int* in_sizes, int n_in,
                              void* d_out, int out_size, void* d_ws, size_t ws_size,
                              hipStream_t stream) {
    const float* ja   = (const float*)d_in[0];
    const float* axes = (const float*)d_in[1];
    const float* orig = (const float*)d_in[2];
    const float* mmul = (const float*)d_in[3];
    const float* moff = (const float*)d_in[4];
    const int*   ctrl = (const int*)d_in[5];
    const int*   msrc = (const int*)d_in[6];
    const int*   mdst = (const int*)d_in[7];
    const int*   typs = (const int*)d_in[8];
    float* out = (float*)d_out;

    const int B = in_sizes[0] / NDOF;
    const int grid = (B + BLOCK - 1) / BLOCK;
    fk_kernel<<<grid, BLOCK, 0, stream>>>(ja, axes, orig, mmul, moff,
                                          ctrl, msrc, mdst, typs, out, B);
}

// Round 2
// 170.577 us; speedup vs baseline: 1.0780x; 1.0780x over previous
//
#include <hip/hip_runtime.h>
#include <math.h>

#define BLOCK 256
#define NF 32
#define NDOF 29
// padded LDS strides
#define ANG_STRIDE 257            // floats per slot-row (29 rows)
#define OUT_STRIDE_F4 9           // float4 per thread-slot (8 data + 1 pad)

__global__ __launch_bounds__(BLOCK) void fk_kernel(
    const float* __restrict__ ja,       // (B,29)
    const float* __restrict__ axes,     // (32,3)
    const float* __restrict__ origins,  // (32,4,4)
    const float* __restrict__ mmul,     // (2,)
    const float* __restrict__ moff,     // (2,)
    const int*   __restrict__ ctrl,     // (29,)
    const int*   __restrict__ msrc,     // (2,)
    const int*   __restrict__ mdst,     // (2,)
    const int*   __restrict__ types,    // (32,)
    float*       __restrict__ out,      // (B,32,4,4)
    int B)
{
    __shared__ float s_ax[NF][3];
    __shared__ float s_or[NF][12];                // top 3 rows of each origin
    __shared__ int   s_type[NF];
    __shared__ int   s_slot[NF];
    __shared__ float s_mult[NF];
    __shared__ float s_off[NF];
    __shared__ float s_ang[NDOF * ANG_STRIDE];    // transposed angles [slot][batch]
    __shared__ float4 s_out[BLOCK * OUT_STRIDE_F4]; // 2-frame output staging

    const int tid = threadIdx.x;

    if (tid < NF) {
        const int f = tid;
        s_ax[f][0] = axes[f*3+0];
        s_ax[f][1] = axes[f*3+1];
        s_ax[f][2] = axes[f*3+2];
        #pragma unroll
        for (int r = 0; r < 3; ++r)
            #pragma unroll
            for (int c = 0; c < 4; ++c)
                s_or[f][r*4+c] = origins[f*16 + r*4 + c];
        s_type[f] = types[f];
        // fold ctrl scatter + mimic joints into: angle = mult * ja[slot] + off
        int slot = -1;
        for (int j = 0; j < NDOF; ++j) if (ctrl[j] == f) slot = j;
        float mu = 1.0f, of = 0.0f;
        for (int m = 0; m < 2; ++m) {
            if (mdst[m] == f) {
                const int sf = msrc[m];
                for (int j = 0; j < NDOF; ++j) if (ctrl[j] == sf) slot = j;
                mu = mmul[m]; of = moff[m];
            }
        }
        s_slot[f] = slot; s_mult[f] = mu; s_off[f] = of;
    }

    // coalesced stage of this block's joint angles into transposed LDS
    const long blk0 = (long)blockIdx.x * BLOCK;
    {
        const long base = blk0 * NDOF;
        const long lim  = (long)B * NDOF;
        for (int i = tid; i < BLOCK * NDOF; i += BLOCK) {
            const long g = base + i;
            const int slot = i % NDOF;
            const int brel = i / NDOF;
            s_ang[slot * ANG_STRIDE + brel] = (g < lim) ? ja[g] : 0.0f;
        }
    }
    __syncthreads();

    float Pr[9], Pt[3];   // running chain pose (3x4 affine)
    float Qr[9], Qt[3];   // saved pose of frame 10 (for leaves 30,31)

    auto compute_local = [&](int f, float* Lr, float* Lt) {
        const int   slot = s_slot[f];
        const float a = (slot >= 0)
            ? fmaf(s_mult[f], s_ang[slot * ANG_STRIDE + tid], s_off[f]) : 0.0f;
        const float wx = a * s_ax[f][0];
        const float wy = a * s_ax[f][1];
        const float wz = a * s_ax[f][2];
        const int ty = s_type[f];
        float R0,R1,R2,R3,R4,R5,R6,R7,R8;
        if (ty == 1) {
            const float t2 = wx*wx + wy*wy + wz*wz;
            const float th = sqrtf(t2 + 1e-18f);
            const float inv = 1.0f / th;
            const float kx = wx*inv, ky = wy*inv, kz = wz*inv;
            float s, c;
            __sincosf(th, &s, &c);
            const float v = 1.0f - c;
            R0 = fmaf(v*kx, kx, c);
            R1 = v*kx*ky - s*kz;
            R2 = v*kx*kz + s*ky;
            R3 = v*kx*ky + s*kz;
            R4 = fmaf(v*ky, ky, c);
            R5 = v*ky*kz - s*kx;
            R6 = v*kx*kz - s*ky;
            R7 = v*ky*kz + s*kx;
            R8 = fmaf(v*kz, kz, c);
        } else {
            R0=1.f;R1=0.f;R2=0.f;R3=0.f;R4=1.f;R5=0.f;R6=0.f;R7=0.f;R8=1.f;
        }
        float tx, tyv, tz;
        if (ty == 2) { tx = wx; tyv = wy; tz = wz; }
        else         { tx = 0.f; tyv = 0.f; tz = 0.f; }
        const float* O = s_or[f];
        #pragma unroll
        for (int r = 0; r < 3; ++r) {
            const float o0 = O[r*4+0], o1 = O[r*4+1], o2 = O[r*4+2], o3 = O[r*4+3];
            Lr[r*3+0] = o0*R0 + o1*R3 + o2*R6;
            Lr[r*3+1] = o0*R1 + o1*R4 + o2*R7;
            Lr[r*3+2] = o0*R2 + o1*R5 + o2*R8;
            Lt[r]     = o0*tx + o1*tyv + o2*tz + o3;
        }
    };

    float4* const out4 = (float4*)out;

    // 16 chunks of 2 frames each; frames 0..29 serial chain, 30/31 off frame 10
    #pragma unroll 1
    for (int c = 0; c < 16; ++c) {
        const int f0 = 2 * c;
        #pragma unroll
        for (int lf = 0; lf < 2; ++lf) {
            const int f = f0 + lf;
            float Lr[9], Lt[3];
            compute_local(f, Lr, Lt);
            float Wr[9], Wt[3];       // pose to write for this frame
            if (f == 0) {
                #pragma unroll
                for (int i = 0; i < 9; ++i) Wr[i] = Lr[i];
                Wt[0]=Lt[0]; Wt[1]=Lt[1]; Wt[2]=Lt[2];
            } else if (f <= 29) {
                #pragma unroll
                for (int r = 0; r < 3; ++r) {
                    const float p0 = Pr[r*3+0], p1 = Pr[r*3+1], p2 = Pr[r*3+2];
                    Wr[r*3+0] = p0*Lr[0] + p1*Lr[3] + p2*Lr[6];
                    Wr[r*3+1] = p0*Lr[1] + p1*Lr[4] + p2*Lr[7];
                    Wr[r*3+2] = p0*Lr[2] + p1*Lr[5] + p2*Lr[8];
                    Wt[r]     = p0*Lt[0] + p1*Lt[1] + p2*Lt[2] + Pt[r];
                }
            } else { // f = 30,31: child of frame 10 (pose saved in Q)
                #pragma unroll
                for (int r = 0; r < 3; ++r) {
                    const float p0 = Qr[r*3+0], p1 = Qr[r*3+1], p2 = Qr[r*3+2];
                    Wr[r*3+0] = p0*Lr[0] + p1*Lr[3] + p2*Lr[6];
                    Wr[r*3+1] = p0*Lr[1] + p1*Lr[4] + p2*Lr[7];
                    Wr[r*3+2] = p0*Lr[2] + p1*Lr[5] + p2*Lr[8];
                    Wt[r]     = p0*Lt[0] + p1*Lt[1] + p2*Lt[2] + Qt[r];
                }
            }
            if (f <= 29) {
                #pragma unroll
                for (int i = 0; i < 9; ++i) Pr[i] = Wr[i];
                Pt[0]=Wt[0]; Pt[1]=Wt[1]; Pt[2]=Wt[2];
                if (f == 10) {
                    #pragma unroll
                    for (int i = 0; i < 9; ++i) Qr[i] = Pr[i];
                    Qt[0]=Pt[0]; Qt[1]=Pt[1]; Qt[2]=Pt[2];
                }
            }
            // stage this frame's 4x4 pose into padded LDS slot
            float4* slot4 = &s_out[tid * OUT_STRIDE_F4 + lf * 4];
            slot4[0] = make_float4(Wr[0], Wr[1], Wr[2], Wt[0]);
            slot4[1] = make_float4(Wr[3], Wr[4], Wr[5], Wt[1]);
            slot4[2] = make_float4(Wr[6], Wr[7], Wr[8], Wt[2]);
            slot4[3] = make_float4(0.0f, 0.0f, 0.0f, 1.0f);
        }
        __syncthreads();
        // cooperative fully-coalesced store: 8 batches x contiguous 128B per wave-instr
        #pragma unroll
        for (int k = 0; k < 8; ++k) {
            const int i = tid + k * BLOCK;
            const int brel = i >> 3;
            const int q    = i & 7;
            const long bb  = blk0 + brel;
            if (bb < (long)B)
                out4[bb * 128 + f0 * 4 + q] = s_out[brel * OUT_STRIDE_F4 + q];
        }
        __syncthreads();
    }
}

extern "C" void kernel_launch(void* const* d_in, const int* in_sizes, int n_in,
                              void* d_out, int out_size, void* d_ws, size_t ws_size,
                              hipStream_t stream) {
    const float* ja   = (const float*)d_in[0];
    const float* axes = (const float*)d_in[1];
    const float* orig = (const float*)d_in[2];
    const float* mmul = (const float*)d_in[3];
    const float* moff = (const float*)d_in[4];
    const int*   ctrl = (const int*)d_in[5];
    const int*   msrc = (const int*)d_in[6];
    const int*   mdst = (const int*)d_in[7];
    const int*   typs = (const int*)d_in[8];
    float* out = (float*)d_out;

    const int B = in_sizes[0] / NDOF;
    const int grid = (B + BLOCK - 1) / BLOCK;
    fk_kernel<<<grid, BLOCK, 0, stream>>>(ja, axes, orig, mmul, moff,
                                          ctrl, msrc, mdst, typs, out, B);
}